// Round 3
// baseline (294.779 us; speedup 1.0000x reference)
//
#include <hip/hip_runtime.h>
#include <hip/hip_bf16.h>

// Problem constants
#define B_ 16
#define T_ 1024
#define D_ 1024

using frag8  = __attribute__((ext_vector_type(8))) short;   // 8 bf16 (4 VGPRs)
using f32x4  = __attribute__((ext_vector_type(4))) float;   // 4 fp32 acc
using u16x8  = __attribute__((ext_vector_type(8))) unsigned short; // 16B chunk

__device__ inline unsigned short f2bf(float f) {
    union { float f; unsigned u; } v; v.f = f;
    unsigned r = v.u + 0x7FFF + ((v.u >> 16) & 1);   // round-nearest-even
    return (unsigned short)(r >> 16);
}
__device__ inline float bf2f(unsigned short u) {
    union { unsigned u; float f; } v; v.u = ((unsigned)u) << 16;
    return v.f;
}

// ---------------------------------------------------------------------------
// K0b: weight-bias vectors (fp32, exact):
//  y=0: w1[e] = Wk[e]·bq     y=1: w2[e] = Wq[e]·bk
//  y=2: c[q]  = Wfc_row(q)·bv   y=3 (block 0 only): bkbq = bk·bq
// grid (256, 4), block 256 (4 waves, 1 row/wave).
// ---------------------------------------------------------------------------
__global__ __launch_bounds__(256)
void wvec(const float* __restrict__ Wq, const float* __restrict__ Wk,
          const float* __restrict__ Wfc,
          const float* __restrict__ bq, const float* __restrict__ bk,
          const float* __restrict__ bv,
          float* __restrict__ w1, float* __restrict__ w2,
          float* __restrict__ cvec, float* __restrict__ bkbq) {
    const int y = blockIdx.y;
    const int tid = threadIdx.x, lane = tid & 63, wave = tid >> 6;
    if (y == 3) {
        if (blockIdx.x != 0) return;
        float s = 0.f;
#pragma unroll
        for (int p = 0; p < 4; ++p) { int i = tid + p * 256; s += bk[i] * bq[i]; }
#pragma unroll
        for (int off = 32; off; off >>= 1) s += __shfl_down(s, off);
        __shared__ float sm[4];
        if (lane == 0) sm[wave] = s;
        __syncthreads();
        if (tid == 0) bkbq[0] = sm[0] + sm[1] + sm[2] + sm[3];
        return;
    }
    const float* Wsrc; const float* bvv; float* outp;
    if (y == 0)      { Wsrc = Wk;  bvv = bq; outp = w1; }
    else if (y == 1) { Wsrc = Wq;  bvv = bk; outp = w2; }
    else             { Wsrc = Wfc; bvv = bv; outp = cvec; }
    const int row = blockIdx.x * 4 + wave;
    const float* r = Wsrc + (size_t)row * D_;
    float s = 0.f;
#pragma unroll
    for (int it = 0; it < 4; ++it) {
        float4 a = *(const float4*)&r[it * 256 + lane * 4];
        float4 b = *(const float4*)&bvv[it * 256 + lane * 4];
        s += a.x * b.x + a.y * b.y + a.z * b.z + a.w * b.w;
    }
#pragma unroll
    for (int off = 32; off; off >>= 1) s += __shfl_down(s, off);
    if (lane == 0) outp[row] = s;
}

// ---------------------------------------------------------------------------
// K0c: FUSED x fp32 -> bf16 cast + u/v row dots (single pass over x).
//  xb[row] = bf16(x[row]);  u[row] = x[row]·w1;  v[row] = x[row]·w2 + bkbq.
// grid 4096, block 256 (4 waves, 1 row/wave); coalesced float4/ushort4.
// ---------------------------------------------------------------------------
__global__ __launch_bounds__(256)
void cvt_x_uv(const float* __restrict__ x, unsigned short* __restrict__ xb,
              const float* __restrict__ w1, const float* __restrict__ w2,
              const float* __restrict__ bkbq,
              float* __restrict__ u, float* __restrict__ v) {
    __shared__ float s1[1024], s2[1024];
    const int tid = threadIdx.x, lane = tid & 63, wave = tid >> 6;
#pragma unroll
    for (int p = 0; p < 4; ++p) {
        int i = tid + p * 256;
        s1[i] = w1[i]; s2[i] = w2[i];
    }
    __syncthreads();
    const int row = blockIdx.x * 4 + wave;
    const float* xr = x + (size_t)row * D_;
    unsigned short* xo = xb + (size_t)row * D_;
    float du = 0.f, dv = 0.f;
#pragma unroll
    for (int k = 0; k < 4; ++k) {
        const int e0 = k * 256 + lane * 4;
        float4 a = *(const float4*)&xr[e0];
        ushort4 o;
        o.x = f2bf(a.x); o.y = f2bf(a.y); o.z = f2bf(a.z); o.w = f2bf(a.w);
        *(ushort4*)&xo[e0] = o;
        du += a.x * s1[e0] + a.y * s1[e0 + 1] + a.z * s1[e0 + 2] + a.w * s1[e0 + 3];
        dv += a.x * s2[e0] + a.y * s2[e0 + 1] + a.z * s2[e0 + 2] + a.w * s2[e0 + 3];
    }
#pragma unroll
    for (int off = 32; off; off >>= 1) {
        du += __shfl_down(du, off);
        dv += __shfl_down(dv, off);
    }
    if (lane == 0) { u[row] = du; v[row] = dv + bkbq[0]; }
}

// ---------------------------------------------------------------------------
// K1 (NEW): small weight-product GEMMs with INLINE fp32->bf16 conversion
// (replaces cvt_w4 + bf16-staged small_gemm; bit-identical: same f2bf
// rounding then same MFMA order).  1024x1024x1024 each:
//  z=0: NT[f][e] = sum_d bf(Wq[f][d])·bf(Wk[e][d])   -> ntb
//  z=1: M [q][e] = sum_d bf(Wfc[q][d])·bf(Wv[e][d])  -> mb
// Staging: reg-stage float4 x4 -> f2bf -> 2x ds_write_b128 per panel.
// LDS XOR swizzle (elem ^= (row&7)<<3) on BOTH write and fragment-read
// sides -> ~2-4-way conflicts instead of 16-way.  Global loads issue
// before the barrier so HBM latency hides under the previous MFMA phase.
// grid (8, 8, 2) block 256.
// ---------------------------------------------------------------------------
__global__ __launch_bounds__(256)
void small_gemm(const float* __restrict__ Wq, const float* __restrict__ Wk,
                const float* __restrict__ Wfc, const float* __restrict__ Wv,
                unsigned short* __restrict__ ntb,
                unsigned short* __restrict__ mb) {
    __shared__ __align__(16) unsigned short As[128 * 32];
    __shared__ __align__(16) unsigned short Bs[128 * 32];

    const int z  = blockIdx.z;
    const int n0 = blockIdx.x * 128;
    const int m0 = blockIdx.y * 128;
    const float* A  = z ? Wfc : Wq;
    const float* Bm = z ? Wv  : Wk;
    unsigned short* out = z ? mb : ntb;

    const int tid = threadIdx.x, lane = tid & 63, wave = tid >> 6;
    const int wm = (wave >> 1) * 64, wn = (wave & 1) * 64;

    f32x4 acc[4][4];
#pragma unroll
    for (int i = 0; i < 4; i++)
#pragma unroll
        for (int j = 0; j < 4; j++) acc[i][j] = (f32x4){0.f, 0.f, 0.f, 0.f};

    const int row = tid >> 1;            // 0..127 staging row
    const int seg = (tid & 1) * 16;      // col offset (elements)
    const int wsw = (row & 7) << 3;      // write-side elem XOR
    const int we0 = (row * 32 + seg) ^ wsw;
    const int we1 = (row * 32 + seg + 8) ^ wsw;
    const int fr = lane & 15, fk = (lane >> 4) * 8;
    const int rsw = (fr & 7) << 3;       // read-side elem XOR (row&7 == fr&7)

    for (int k0 = 0; k0 < D_; k0 += 32) {
        const float* ar = A  + (size_t)(m0 + row) * D_ + k0 + seg;
        const float* br = Bm + (size_t)(n0 + row) * D_ + k0 + seg;
        float4 a0 = ((const float4*)ar)[0], a1 = ((const float4*)ar)[1];
        float4 a2 = ((const float4*)ar)[2], a3 = ((const float4*)ar)[3];
        float4 b0 = ((const float4*)br)[0], b1 = ((const float4*)br)[1];
        float4 b2 = ((const float4*)br)[2], b3 = ((const float4*)br)[3];
        u16x8 pa0, pa1, pb0, pb1;
        pa0[0]=f2bf(a0.x); pa0[1]=f2bf(a0.y); pa0[2]=f2bf(a0.z); pa0[3]=f2bf(a0.w);
        pa0[4]=f2bf(a1.x); pa0[5]=f2bf(a1.y); pa0[6]=f2bf(a1.z); pa0[7]=f2bf(a1.w);
        pa1[0]=f2bf(a2.x); pa1[1]=f2bf(a2.y); pa1[2]=f2bf(a2.z); pa1[3]=f2bf(a2.w);
        pa1[4]=f2bf(a3.x); pa1[5]=f2bf(a3.y); pa1[6]=f2bf(a3.z); pa1[7]=f2bf(a3.w);
        pb0[0]=f2bf(b0.x); pb0[1]=f2bf(b0.y); pb0[2]=f2bf(b0.z); pb0[3]=f2bf(b0.w);
        pb0[4]=f2bf(b1.x); pb0[5]=f2bf(b1.y); pb0[6]=f2bf(b1.z); pb0[7]=f2bf(b1.w);
        pb1[0]=f2bf(b2.x); pb1[1]=f2bf(b2.y); pb1[2]=f2bf(b2.z); pb1[3]=f2bf(b2.w);
        pb1[4]=f2bf(b3.x); pb1[5]=f2bf(b3.y); pb1[6]=f2bf(b3.z); pb1[7]=f2bf(b3.w);

        __syncthreads();            // previous iteration's reads complete
        *(u16x8*)&As[we0] = pa0;
        *(u16x8*)&As[we1] = pa1;
        *(u16x8*)&Bs[we0] = pb0;
        *(u16x8*)&Bs[we1] = pb1;
        __syncthreads();

        frag8 af[4], bff[4];
#pragma unroll
        for (int t = 0; t < 4; ++t)
            af[t] = *(const frag8*)&As[(((wm + t * 16 + fr) * 32) + fk) ^ rsw];
#pragma unroll
        for (int t = 0; t < 4; ++t)
            bff[t] = *(const frag8*)&Bs[(((wn + t * 16 + fr) * 32) + fk) ^ rsw];
#pragma unroll
        for (int i = 0; i < 4; i++)
#pragma unroll
            for (int j = 0; j < 4; j++)
                acc[i][j] = __builtin_amdgcn_mfma_f32_16x16x32_bf16(
                    af[i], bff[j], acc[i][j], 0, 0, 0);
    }

    const int col   = lane & 15;
    const int rbase = (lane >> 4) * 4;
#pragma unroll
    for (int i = 0; i < 4; i++) {
#pragma unroll
        for (int j = 0; j < 4; j++) {
            int gn = n0 + wn + j * 16 + col;
#pragma unroll
            for (int r = 0; r < 4; r++) {
                int gm = m0 + wm + i * 16 + rbase + r;
                out[(size_t)gm * D_ + gn] = f2bf(acc[i][j][r]);
            }
        }
    }
}

// ---------------------------------------------------------------------------
// Shared 256x256 8-phase main-loop machinery (verified rounds 1-2), now
// with BALANCED ds_reads (12/4/8/0 per phase instead of 16/0/8/0):
//  P0 {LDA(i0), LDB[0..1], stage (T+1).Ah1}, P1 {LDB[2..3]},
//  P2 {LDA(i1), stage (T+2).Bh0+Bh1}, P3 {stage (T+2).Ah0; vmcnt(6)}.
// Region safety: both B halves read in P0 (rows bro+0..31) AND P1 (rows
// bro+32..63) -> B stages must be >=P2 (they are).  A halves read P0+P2
// -> Ah0 stage at P3; Ah1 stage targets the OTHER buffer.  vmcnt(6) at
// T.P3 drains everything through T.P0 (tile T+1 fully resident), leaving
// {T.P2 B(4), T.P3 Ah0(2)} = 6 in flight.  Prologue = 7 pairs, vmcnt(6)
// leaves {B[1](4), A[1]h0(2)} = same invariant.  Tail stages clamp kcol
// to tile 15 (regions never read again).
// ---------------------------------------------------------------------------
#define BARRIER() do { __builtin_amdgcn_s_barrier(); \
                       __builtin_amdgcn_sched_barrier(0); } while (0)

#define STG(ldsoff, panel, kcol)                                               \
    do {                                                                       \
        __builtin_amdgcn_global_load_lds(                                      \
            (const __attribute__((address_space(1))) unsigned int*)            \
                ((panel) + soff0 + (kcol)),                                    \
            (__attribute__((address_space(3))) unsigned int*)                  \
                (lds_pg + (ldsoff) + dstw), 16, 0, 0);                         \
        __builtin_amdgcn_global_load_lds(                                      \
            (const __attribute__((address_space(1))) unsigned int*)            \
                ((panel) + soff1 + (kcol)),                                    \
            (__attribute__((address_space(3))) unsigned int*)                  \
                (lds_pg + (ldsoff) + 4096 + dstw), 16, 0, 0);                  \
    } while (0)

#define LDA(IH)                                                                \
    _Pragma("unroll")                                                          \
    for (int t = 0; t < 4; ++t) {                                              \
        const int rbb = abase + ((IH) * 64 + t * 16 + fr) * 64;                \
        af[t][0] = *(const frag8*)&lds_pg[rbb + sl0];                          \
        af[t][1] = *(const frag8*)&lds_pg[rbb + sl1];                          \
    }
#define LDB2(J0)                                                               \
    _Pragma("unroll")                                                          \
    for (int j = (J0); j < (J0) + 2; ++j) {                                    \
        const int rbb = bbase + (bro + j * 16 + fr) * 64;                      \
        bf[j][0] = *(const frag8*)&lds_pg[rbb + sl0];                          \
        bf[j][1] = *(const frag8*)&lds_pg[rbb + sl1];                          \
    }
#define MFMA_Q(I0, J0)                                                         \
    __builtin_amdgcn_s_setprio(1);                                             \
    _Pragma("unroll")                                                          \
    for (int t = 0; t < 4; ++t) {                                              \
        _Pragma("unroll")                                                      \
        for (int jj = 0; jj < 2; ++jj) {                                       \
            acc[(I0)+t][(J0)+jj] = __builtin_amdgcn_mfma_f32_16x16x32_bf16(    \
                af[t][0], bf[(J0)+jj][0], acc[(I0)+t][(J0)+jj], 0, 0, 0);      \
            acc[(I0)+t][(J0)+jj] = __builtin_amdgcn_mfma_f32_16x16x32_bf16(    \
                af[t][1], bf[(J0)+jj][1], acc[(I0)+t][(J0)+jj], 0, 0, 0);      \
        }                                                                      \
    }                                                                          \
    __builtin_amdgcn_s_setprio(0);

#define MAIN_LOOP_8PHASE(PA0, PA1, PB0, PB1)                                   \
    STG(0,             PA0, 0);                                                \
    STG(8192,          PA1, 0);                                                \
    STG(16384,         PB0, 0);                                                \
    STG(24576,         PB1, 0);                                                \
    STG(32768 + 16384, PB0, 64);                                               \
    STG(32768 + 24576, PB1, 64);                                               \
    STG(32768 + 0,     PA0, 64);                                               \
    asm volatile("s_waitcnt vmcnt(6)" ::: "memory");                           \
    BARRIER();                                                                 \
    _Pragma("unroll")                                                          \
    for (int i = 0; i < 8; i++)                                                \
        _Pragma("unroll")                                                      \
        for (int j = 0; j < 4; j++) acc[i][j] = (f32x4){0.f, 0.f, 0.f, 0.f};   \
    for (int T = 0; T < 16; ++T) {                                             \
        const int cbase = (T & 1) << 15;                                       \
        const int obase = cbase ^ 32768;                                       \
        const int abase = cbase + aregw;                                       \
        const int bbase = cbase + bregw;                                       \
        const int kc1 = (T + 1 < 16 ? T + 1 : 15) * 64;                        \
        const int kc2 = (T + 2 < 16 ? T + 2 : 15) * 64;                        \
        LDA(0)                                                                 \
        LDB2(0)                                                                \
        STG(obase + 8192, PA1, kc1);                                           \
        BARRIER();                                                             \
        MFMA_Q(0, 0)                                                           \
        BARRIER();                                                             \
        LDB2(2)                                                                \
        BARRIER();                                                             \
        MFMA_Q(0, 2)                                                           \
        BARRIER();                                                             \
        LDA(1)                                                                 \
        STG(cbase + 16384, PB0, kc2);                                          \
        STG(cbase + 24576, PB1, kc2);                                          \
        BARRIER();                                                             \
        MFMA_Q(4, 2)                                                           \
        BARRIER();                                                             \
        STG(cbase + 0, PA0, kc2);                                              \
        asm volatile("s_waitcnt vmcnt(6)" ::: "memory");                       \
        BARRIER();                                                             \
        MFMA_Q(4, 0)                                                           \
        BARRIER();                                                             \
    }                                                                          \
    asm volatile("s_waitcnt vmcnt(0)" ::: "memory");

// ---------------------------------------------------------------------------
// K2: fused P/G GEMM, 256x256-tile 8-phase.  A = xb (M=16384, K=1024):
//  z=0: P[i][f] = sum_e x[i][e]·NT[f][e]           -> pb (row-major bf16)
//  z=1: G[i][q] = sum_e x[i][e]·M[q][e] + c[q]     -> gbuf per-thread-slot
//       layout: tile(mt*4+nt)*65536 + (i*2+jp)*4096 + tid*8 + (j&1)*4 + r
// grid 512; XCD swizzle keeps 8 consecutive A-panels per XCD.
// ---------------------------------------------------------------------------
__global__ __launch_bounds__(512, 2)
void pg_gemm8(const unsigned short* __restrict__ xb,
              const unsigned short* __restrict__ ntb,
              const unsigned short* __restrict__ mb,
              const float* __restrict__ cvec,
              unsigned short* __restrict__ pb,
              unsigned short* __restrict__ gbuf) {
    extern __shared__ __align__(16) unsigned short lds_pg[];

    const int bid = blockIdx.x;
    const int logical = (bid & 7) * 64 + (bid >> 3);
    const int mt = logical >> 3;          // 0..63
    const int z  = (logical >> 2) & 1;
    const int nt = logical & 3;           // 0..3
    const int m0 = mt * 256, n0 = nt * 256;

    const unsigned short* Bm = z ? mb : ntb;

    const int tid = threadIdx.x, lane = tid & 63, w = tid >> 6;
    const int fr = lane & 15, ls = lane >> 4, f7 = fr & 7;

    const int ssl   = ((tid & 7) ^ ((tid >> 3) & 7)) * 8;      // elements
    const int soff0 = (tid >> 3) * 1024 + ssl;
    const int soff1 = soff0 + 64 * 1024;
    const int dstw  = w * 512;                                 // u16

    const unsigned short* pA0 = xb  + (size_t)m0 * 1024;
    const unsigned short* pA1 = pA0 + (size_t)128 * 1024;
    const unsigned short* pB0 = Bm  + (size_t)n0 * 1024;
    const unsigned short* pB1 = pB0 + (size_t)128 * 1024;

    const int aregw = (w >> 2) * 8192;                  // wave's A half
    const int bregw = 16384 + ((w & 3) >> 1) * 8192;    // wave's B half
    const int bro   = (w & 1) * 64;                     // n-offset in B half
    const int sl0   = (ls ^ f7) << 3;                   // kk=0 swz slot (elems)
    const int sl1   = ((4 + ls) ^ f7) << 3;             // kk=1

    f32x4 acc[8][4];
    frag8 af[4][2], bf[4][2];

    MAIN_LOOP_8PHASE(pA0, pA1, pB0, pB1)

    // epilogue
    const int wm = (w >> 2) * 128, wn = (w & 3) * 64;
    const int rb4 = ls * 4;
    if (z == 0) {
        // P: row-major store (consumed via global_load_lds row staging)
#pragma unroll
        for (int i = 0; i < 8; ++i)
#pragma unroll
            for (int j = 0; j < 4; ++j) {
                const int gm = m0 + wm + i * 16 + rb4;
                const int gn = n0 + wn + j * 16 + fr;
#pragma unroll
                for (int r = 0; r < 4; ++r)
                    pb[(size_t)(gm + r) * 1024 + gn] = f2bf(acc[i][j][r]);
            }
    } else {
        // G: per-thread-slot layout, 16 coalesced 16B stores
        float bb[4];
#pragma unroll
        for (int j = 0; j < 4; ++j) bb[j] = cvec[n0 + wn + j * 16 + fr];
        unsigned short* Gt = gbuf + ((size_t)(mt * 4 + nt) << 16) + tid * 8;
#pragma unroll
        for (int i = 0; i < 8; ++i) {
#pragma unroll
            for (int jp = 0; jp < 2; ++jp) {
                u16x8 o;
#pragma unroll
                for (int e = 0; e < 8; ++e) {
                    const int j = jp * 2 + (e >> 2), r = e & 3;
                    o[e] = f2bf(acc[i][j][r] + bb[j]);
                }
                *(u16x8*)(Gt + (size_t)(i * 2 + jp) * 4096) = o;
            }
        }
    }
}

// ---------------------------------------------------------------------------
// K3: score + exp + G-weighted row reduction, 256x256 8-phase.
// S[i][j] = sum_f P[b·T+i][f]·x[b·T+j][f] + u[i] + v[j]; p = exp(S*scale).
// G read back from per-thread-slot gbuf (identical geometry as producer).
// Partials: chunk t = jt*4+(w&3); lpart/Apart[((b*8+i0b)*16+t)*128+row],
// i0b=it*2+(w>>2); every slot written exactly once; finalize unchanged.
// grid 256.
// ---------------------------------------------------------------------------
__global__ __launch_bounds__(512, 2)
void score_attn8(const unsigned short* __restrict__ pbuf,
                 const unsigned short* __restrict__ xb,
                 const unsigned short* __restrict__ gb,
                 const float* __restrict__ u, const float* __restrict__ v,
                 float* __restrict__ lpart, float* __restrict__ Apart) {
    extern __shared__ __align__(16) unsigned short lds_pg[];

    const int bid = blockIdx.x;
    const int logical = (bid & 7) * 32 + (bid >> 3);
    const int b  = logical >> 4;          // 0..15
    const int it = (logical >> 2) & 3;    // i-tile (256 rows)
    const int jt = logical & 3;           // j-tile (256 cols)

    const int tid = threadIdx.x, lane = tid & 63, w = tid >> 6;
    const int fr = lane & 15, ls = lane >> 4, f7 = fr & 7;

    const int ssl   = ((tid & 7) ^ ((tid >> 3) & 7)) * 8;      // elements
    const int soff0 = (tid >> 3) * 1024 + ssl;
    const int soff1 = soff0 + 64 * 1024;
    const int dstw  = w * 512;                                 // u16

    const unsigned short* pA0 = pbuf + (size_t)(b * 1024 + it * 256) * 1024;
    const unsigned short* pA1 = pA0  + (size_t)128 * 1024;
    const unsigned short* pB0 = xb   + (size_t)(b * 1024 + jt * 256) * 1024;
    const unsigned short* pB1 = pB0  + (size_t)128 * 1024;

    const int aregw = (w >> 2) * 8192;
    const int bregw = 16384 + ((w & 3) >> 1) * 8192;
    const int bro   = (w & 1) * 64;
    const int sl0   = (ls ^ f7) << 3;
    const int sl1   = ((4 + ls) ^ f7) << 3;

    f32x4 acc[8][4];
    frag8 af[4][2], bf[4][2];

    MAIN_LOOP_8PHASE(pA0, pA1, pB0, pB1)

    // epilogue: p = exp((S + u[i] + v[j])*scale); reduce p and p*G over cols
    const float scale = 0.03125f;   // 1/sqrt(1024)
    const int wm = (w >> 2) * 128, wn = (w & 3) * 64;
    const float* ub = u + (size_t)b * T_ + it * 256 + wm;
    const float* vb = v + (size_t)b * T_ + jt * 256 + wn;

    float vval[4];
#pragma unroll
    for (int j = 0; j < 4; ++j) vval[j] = vb[j * 16 + fr];

    const unsigned short* Gt =
        gb + ((size_t)((b * 4 + it) * 4 + jt) << 16) + tid * 8;

    const int i0b = it * 2 + (w >> 2);
    const int tch = jt * 4 + (w & 3);
    const size_t base = ((size_t)(b * 8 + i0b) * 16 + tch) * 128;
    float* lrow = lpart + base;
    float* Arow = Apart + base;

#pragma unroll
    for (int i = 0; i < 8; ++i) {
        float uval[4];
#pragma unroll
        for (int r = 0; r < 4; ++r) uval[r] = ub[i * 16 + ls * 4 + r];
        float lp[4] = {0.f, 0.f, 0.f, 0.f}, Ap[4] = {0.f, 0.f, 0.f, 0.f};
#pragma unroll
        for (int jp = 0; jp < 2; ++jp) {
            u16x8 gv = *(const u16x8*)(Gt + (size_t)(i * 2 + jp) * 4096);
#pragma unroll
            for (int e = 0; e < 8; ++e) {
                const int j = jp * 2 + (e >> 2), r = e & 3;
                float p = __expf((acc[i][j][r] + uval[r] + vval[j]) * scale);
                lp[r] += p;
                Ap[r] += p * bf2f(gv[e]);
            }
        }
#pragma unroll
        for (int m = 1; m < 16; m <<= 1) {
#pragma unroll
            for (int r = 0; r < 4; ++r) {
                lp[r] += __shfl_xor(lp[r], m);
                Ap[r] += __shfl_xor(Ap[r], m);
            }
        }
        if (fr == 0) {
#pragma unroll
            for (int r = 0; r < 4; ++r) {
                const int row = i * 16 + ls * 4 + r;
                lrow[row] = lp[r];
                Arow[row] = Ap[r];
            }
        }
    }
}

// ---------------------------------------------------------------------------
// K4: finalize — out[b] = bfc + sum_i (sum_t Apart)/(sum_t lpart).
// Fixed summation order -> bit-deterministic.  grid (16) block 256.
// ---------------------------------------------------------------------------
__global__ __launch_bounds__(256)
void finalize(const float* __restrict__ lpart, const float* __restrict__ Apart,
              const float* __restrict__ bfc, float* __restrict__ out) {
    const int b = blockIdx.x;
    const int tid = threadIdx.x, lane = tid & 63, wave = tid >> 6;
    float s = 0.f;
#pragma unroll
    for (int p = 0; p < 4; ++p) {
        const int rg = tid + p * 256;          // 0..1023 (row index within b)
        const int i0b = rg >> 7, row = rg & 127;
        const size_t base = ((size_t)b * 8 + i0b) * 2048 + row;
        float lsum = 0.f, Asum = 0.f;
#pragma unroll
        for (int t = 0; t < 16; ++t) {         // 64-col chunks, fixed order
            lsum += lpart[base + (size_t)t * 128];
            Asum += Apart[base + (size_t)t * 128];
        }
        s += Asum / lsum;
    }
#pragma unroll
    for (int off = 32; off; off >>= 1) s += __shfl_down(s, off);
    __shared__ float ws_[4];
    if (lane == 0) ws_[wave] = s;
    __syncthreads();
    if (tid == 0) out[b] = ws_[0] + ws_[1] + ws_[2] + ws_[3] + bfc[0];
}

extern "C" void kernel_launch(void* const* d_in, const int* in_sizes, int n_in,
                              void* d_out, int out_size, void* d_ws, size_t ws_size,
                              hipStream_t stream) {
    const float* x   = (const float*)d_in[0];
    const float* Wq  = (const float*)d_in[1];
    const float* bq  = (const float*)d_in[2];
    const float* Wk  = (const float*)d_in[3];
    const float* bk  = (const float*)d_in[4];
    const float* Wv  = (const float*)d_in[5];
    const float* bv  = (const float*)d_in[6];
    const float* Wfc = (const float*)d_in[7];
    const float* bfc = (const float*)d_in[8];
    float* out = (float*)d_out;

    // one-time: allow 128 KiB dynamic LDS (host-side, capture-safe)
    static bool attr_set = false;
    if (!attr_set) {
        hipFuncSetAttribute((const void*)pg_gemm8,
                            hipFuncAttributeMaxDynamicSharedMemorySize, 131072);
        hipFuncSetAttribute((const void*)score_attn8,
                            hipFuncAttributeMaxDynamicSharedMemorySize, 131072);
        attr_set = true;
    }

    // workspace layout (~102.3 MB), every byte written before read each call:
    char* ws = (char*)d_ws;
    unsigned short* xb    = (unsigned short*)ws;                   // 32 MB
    unsigned short* ntb   = xb   + (size_t)B_ * T_ * D_;           // 2 MB
    unsigned short* mb    = ntb  + (size_t)D_ * D_;                // 2 MB
    unsigned short* pb    = mb   + (size_t)D_ * D_;                // 32 MB
    unsigned short* gbuf  = pb   + (size_t)B_ * T_ * D_;           // 32 MB
    float*          w1    = (float*)(gbuf + (size_t)B_ * T_ * T_); // 4 KB
    float*          w2    = w1 + D_;                               // 4 KB
    float*          cvec  = w2 + D_;                               // 4 KB
    float*          bkbq  = cvec + D_;                             // 16 B
    float*          u     = bkbq + 4;                              // 64 KB
    float*          v     = u + (size_t)B_ * T_;                   // 64 KB
    float*          lpart = v + (size_t)B_ * T_;                   // 1 MB
    float*          Apart = lpart + (size_t)B_ * 8 * 8 * 2 * 128;  // 1 MB

    wvec       <<<dim3(256, 4),    256, 0,      stream>>>(Wq, Wk, Wfc, bq, bk, bv, w1, w2, cvec, bkbq);
    small_gemm <<<dim3(8, 8, 2),   256, 0,      stream>>>(Wq, Wk, Wfc, Wv, ntb, mb);
    cvt_x_uv   <<<dim3(4096),      256, 0,      stream>>>(x, xb, w1, w2, bkbq, u, v);
    pg_gemm8   <<<dim3(512),       512, 131072, stream>>>(xb, ntb, mb, cvec, pb, gbuf);
    score_attn8<<<dim3(256),       512, 131072, stream>>>(pb, xb, gbuf, u, v, lpart, Apart);
    finalize   <<<dim3(B_),        256, 0,      stream>>>(lpart, Apart, bfc, out);
}

// Round 4
// 290.675 us; speedup vs baseline: 1.0141x; 1.0141x over previous
//
#include <hip/hip_runtime.h>
#include <hip/hip_bf16.h>

// Problem constants
#define B_ 16
#define T_ 1024
#define D_ 1024

using frag8  = __attribute__((ext_vector_type(8))) short;   // 8 bf16 (4 VGPRs)
using f32x4  = __attribute__((ext_vector_type(4))) float;   // 4 fp32 acc
using u16x8  = __attribute__((ext_vector_type(8))) unsigned short; // 16B chunk

__device__ inline unsigned short f2bf(float f) {
    union { float f; unsigned u; } v; v.f = f;
    unsigned r = v.u + 0x7FFF + ((v.u >> 16) & 1);   // round-nearest-even
    return (unsigned short)(r >> 16);
}
__device__ inline float bf2f(unsigned short u) {
    union { unsigned u; float f; } v; v.u = ((unsigned)u) << 16;
    return v.f;
}

// ---------------------------------------------------------------------------
// K0 (FUSED): weight prep — one launch, two independent jobs:
//  blocks [0,128):   small weight-product GEMMs with INLINE fp32->bf16
//    z=0: NT[f][e] = sum_d bf(Wq[f][d])·bf(Wk[e][d])   -> ntb
//    z=1: M [q][e] = sum_d bf(Wfc[q][d])·bf(Wv[e][d])  -> mb
//    (reg-stage float4 -> f2bf -> ds_write_b128; XOR swizzle on both
//     write and fragment-read sides; bit-identical to cvt_w4+bf16 GEMM)
//  blocks [128,1152): wvec rows (fp32, exact):
//    y=0: w1[e]=Wk[e]·bq  y=1: w2[e]=Wq[e]·bk  y=2: c[q]=Wfc_row(q)·bv
//    y=3 (one block): bkbq = bk·bq
// GEMM blocks dispatch first (low blockIdx -> critical path starts now);
// wvec's 1024 tiny blocks fill the other half of the GPU concurrently.
// ---------------------------------------------------------------------------
__global__ __launch_bounds__(256)
void prep_w(const float* __restrict__ Wq, const float* __restrict__ Wk,
            const float* __restrict__ Wfc, const float* __restrict__ Wv,
            const float* __restrict__ bq, const float* __restrict__ bk,
            const float* __restrict__ bv,
            unsigned short* __restrict__ ntb, unsigned short* __restrict__ mb,
            float* __restrict__ w1, float* __restrict__ w2,
            float* __restrict__ cvec, float* __restrict__ bkbq) {
    __shared__ __align__(16) unsigned short As[128 * 32];
    __shared__ __align__(16) unsigned short Bs[128 * 32];
    __shared__ float sm[4];

    const int bx = blockIdx.x;
    const int tid = threadIdx.x, lane = tid & 63, wave = tid >> 6;

    if (bx < 128) {
        // ---- small GEMM part ----
        const int z  = bx >> 6;
        const int rem = bx & 63;
        const int n0 = (rem & 7) * 128;
        const int m0 = (rem >> 3) * 128;
        const float* A  = z ? Wfc : Wq;
        const float* Bm = z ? Wv  : Wk;
        unsigned short* out = z ? mb : ntb;

        const int wm = (wave >> 1) * 64, wn = (wave & 1) * 64;

        f32x4 acc[4][4];
#pragma unroll
        for (int i = 0; i < 4; i++)
#pragma unroll
            for (int j = 0; j < 4; j++) acc[i][j] = (f32x4){0.f, 0.f, 0.f, 0.f};

        const int row = tid >> 1;            // 0..127 staging row
        const int seg = (tid & 1) * 16;      // col offset (elements)
        const int wsw = (row & 7) << 3;      // write-side elem XOR
        const int we0 = (row * 32 + seg) ^ wsw;
        const int we1 = (row * 32 + seg + 8) ^ wsw;
        const int fr = lane & 15, fk = (lane >> 4) * 8;
        const int rsw = (fr & 7) << 3;       // read-side elem XOR

        for (int k0 = 0; k0 < D_; k0 += 32) {
            const float* ar = A  + (size_t)(m0 + row) * D_ + k0 + seg;
            const float* br = Bm + (size_t)(n0 + row) * D_ + k0 + seg;
            float4 a0 = ((const float4*)ar)[0], a1 = ((const float4*)ar)[1];
            float4 a2 = ((const float4*)ar)[2], a3 = ((const float4*)ar)[3];
            float4 b0 = ((const float4*)br)[0], b1 = ((const float4*)br)[1];
            float4 b2 = ((const float4*)br)[2], b3 = ((const float4*)br)[3];
            u16x8 pa0, pa1, pb0, pb1;
            pa0[0]=f2bf(a0.x); pa0[1]=f2bf(a0.y); pa0[2]=f2bf(a0.z); pa0[3]=f2bf(a0.w);
            pa0[4]=f2bf(a1.x); pa0[5]=f2bf(a1.y); pa0[6]=f2bf(a1.z); pa0[7]=f2bf(a1.w);
            pa1[0]=f2bf(a2.x); pa1[1]=f2bf(a2.y); pa1[2]=f2bf(a2.z); pa1[3]=f2bf(a2.w);
            pa1[4]=f2bf(a3.x); pa1[5]=f2bf(a3.y); pa1[6]=f2bf(a3.z); pa1[7]=f2bf(a3.w);
            pb0[0]=f2bf(b0.x); pb0[1]=f2bf(b0.y); pb0[2]=f2bf(b0.z); pb0[3]=f2bf(b0.w);
            pb0[4]=f2bf(b1.x); pb0[5]=f2bf(b1.y); pb0[6]=f2bf(b1.z); pb0[7]=f2bf(b1.w);
            pb1[0]=f2bf(b2.x); pb1[1]=f2bf(b2.y); pb1[2]=f2bf(b2.z); pb1[3]=f2bf(b2.w);
            pb1[4]=f2bf(b3.x); pb1[5]=f2bf(b3.y); pb1[6]=f2bf(b3.z); pb1[7]=f2bf(b3.w);

            __syncthreads();            // previous iteration's reads complete
            *(u16x8*)&As[we0] = pa0;
            *(u16x8*)&As[we1] = pa1;
            *(u16x8*)&Bs[we0] = pb0;
            *(u16x8*)&Bs[we1] = pb1;
            __syncthreads();

            frag8 af[4], bff[4];
#pragma unroll
            for (int t = 0; t < 4; ++t)
                af[t] = *(const frag8*)&As[(((wm + t * 16 + fr) * 32) + fk) ^ rsw];
#pragma unroll
            for (int t = 0; t < 4; ++t)
                bff[t] = *(const frag8*)&Bs[(((wn + t * 16 + fr) * 32) + fk) ^ rsw];
#pragma unroll
            for (int i = 0; i < 4; i++)
#pragma unroll
                for (int j = 0; j < 4; j++)
                    acc[i][j] = __builtin_amdgcn_mfma_f32_16x16x32_bf16(
                        af[i], bff[j], acc[i][j], 0, 0, 0);
        }

        const int col   = lane & 15;
        const int rbase = (lane >> 4) * 4;
#pragma unroll
        for (int i = 0; i < 4; i++) {
#pragma unroll
            for (int j = 0; j < 4; j++) {
                int gn = n0 + wn + j * 16 + col;
#pragma unroll
                for (int r = 0; r < 4; r++) {
                    int gm = m0 + wm + i * 16 + rbase + r;
                    out[(size_t)gm * D_ + gn] = f2bf(acc[i][j][r]);
                }
            }
        }
        return;
    }

    // ---- wvec part ----
    const int wvb_ = bx - 128;
    const int y    = wvb_ >> 8;      // 0..3
    const int bxx  = wvb_ & 255;
    if (y == 3) {
        if (bxx != 0) return;
        float s = 0.f;
#pragma unroll
        for (int p = 0; p < 4; ++p) { int i = tid + p * 256; s += bk[i] * bq[i]; }
#pragma unroll
        for (int off = 32; off; off >>= 1) s += __shfl_down(s, off);
        if (lane == 0) sm[wave] = s;
        __syncthreads();
        if (tid == 0) bkbq[0] = sm[0] + sm[1] + sm[2] + sm[3];
        return;
    }
    const float* Wsrc; const float* bvv; float* outp;
    if (y == 0)      { Wsrc = Wk;  bvv = bq; outp = w1; }
    else if (y == 1) { Wsrc = Wq;  bvv = bk; outp = w2; }
    else             { Wsrc = Wfc; bvv = bv; outp = cvec; }
    const int rrow = bxx * 4 + wave;
    const float* r = Wsrc + (size_t)rrow * D_;
    float s = 0.f;
#pragma unroll
    for (int it = 0; it < 4; ++it) {
        float4 a = *(const float4*)&r[it * 256 + lane * 4];
        float4 b = *(const float4*)&bvv[it * 256 + lane * 4];
        s += a.x * b.x + a.y * b.y + a.z * b.z + a.w * b.w;
    }
#pragma unroll
    for (int off = 32; off; off >>= 1) s += __shfl_down(s, off);
    if (lane == 0) outp[rrow] = s;
}

// ---------------------------------------------------------------------------
// K0c: FUSED x fp32 -> bf16 cast + u/v row dots (single pass over x).
//  xb[row] = bf16(x[row]);  u[row] = x[row]·w1;  v[row] = x[row]·w2 + bkbq.
// grid 4096, block 256 (4 waves, 1 row/wave); coalesced float4/ushort4.
// ---------------------------------------------------------------------------
__global__ __launch_bounds__(256)
void cvt_x_uv(const float* __restrict__ x, unsigned short* __restrict__ xb,
              const float* __restrict__ w1, const float* __restrict__ w2,
              const float* __restrict__ bkbq,
              float* __restrict__ u, float* __restrict__ v) {
    __shared__ float s1[1024], s2[1024];
    const int tid = threadIdx.x, lane = tid & 63, wave = tid >> 6;
#pragma unroll
    for (int p = 0; p < 4; ++p) {
        int i = tid + p * 256;
        s1[i] = w1[i]; s2[i] = w2[i];
    }
    __syncthreads();
    const int row = blockIdx.x * 4 + wave;
    const float* xr = x + (size_t)row * D_;
    unsigned short* xo = xb + (size_t)row * D_;
    float du = 0.f, dv = 0.f;
#pragma unroll
    for (int k = 0; k < 4; ++k) {
        const int e0 = k * 256 + lane * 4;
        float4 a = *(const float4*)&xr[e0];
        ushort4 o;
        o.x = f2bf(a.x); o.y = f2bf(a.y); o.z = f2bf(a.z); o.w = f2bf(a.w);
        *(ushort4*)&xo[e0] = o;
        du += a.x * s1[e0] + a.y * s1[e0 + 1] + a.z * s1[e0 + 2] + a.w * s1[e0 + 3];
        dv += a.x * s2[e0] + a.y * s2[e0 + 1] + a.z * s2[e0 + 2] + a.w * s2[e0 + 3];
    }
#pragma unroll
    for (int off = 32; off; off >>= 1) {
        du += __shfl_down(du, off);
        dv += __shfl_down(dv, off);
    }
    if (lane == 0) { u[row] = du; v[row] = dv + bkbq[0]; }
}

// ---------------------------------------------------------------------------
// Shared 256x256 8-phase main-loop machinery — ROUND-2 VERIFIED SCHEDULE
// (R3's 12/4/8/0 rebalance REGRESSED −16%: LDB2(2) on P1's critical path +
//  clustered B stages; reverted to 16/0/8/0):
//  P0 {LDA(i0)+LDBALL; stage (T+1).Ah1}, P1 {stage (T+2).Bh0},
//  P2 {LDA(i1); stage (T+2).Bh1}, P3 {stage (T+2).Ah0; vmcnt(6)}.
// Region safety: B fully read in P0, A fully read by P2; every stage lands
// >=1 end-barrier after the last read of its region; vmcnt(6) at T.P3
// drains through T.P0 (tile T+1 resident), leaving 6 in flight.  Prologue
// = 7 pairs, same invariant.  Tail stages clamp kcol to tile 15.
// ---------------------------------------------------------------------------
#define BARRIER() do { __builtin_amdgcn_s_barrier(); \
                       __builtin_amdgcn_sched_barrier(0); } while (0)

#define STG(ldsoff, panel, kcol)                                               \
    do {                                                                       \
        __builtin_amdgcn_global_load_lds(                                      \
            (const __attribute__((address_space(1))) unsigned int*)            \
                ((panel) + soff0 + (kcol)),                                    \
            (__attribute__((address_space(3))) unsigned int*)                  \
                (lds_pg + (ldsoff) + dstw), 16, 0, 0);                         \
        __builtin_amdgcn_global_load_lds(                                      \
            (const __attribute__((address_space(1))) unsigned int*)            \
                ((panel) + soff1 + (kcol)),                                    \
            (__attribute__((address_space(3))) unsigned int*)                  \
                (lds_pg + (ldsoff) + 4096 + dstw), 16, 0, 0);                  \
    } while (0)

#define LDA(IH)                                                                \
    _Pragma("unroll")                                                          \
    for (int t = 0; t < 4; ++t) {                                              \
        const int rbb = abase + ((IH) * 64 + t * 16 + fr) * 64;                \
        af[t][0] = *(const frag8*)&lds_pg[rbb + sl0];                          \
        af[t][1] = *(const frag8*)&lds_pg[rbb + sl1];                          \
    }
#define LDBALL()                                                               \
    _Pragma("unroll")                                                          \
    for (int j = 0; j < 4; ++j) {                                              \
        const int rbb = bbase + (bro + j * 16 + fr) * 64;                      \
        bf[j][0] = *(const frag8*)&lds_pg[rbb + sl0];                          \
        bf[j][1] = *(const frag8*)&lds_pg[rbb + sl1];                          \
    }
#define MFMA_Q(I0, J0)                                                         \
    __builtin_amdgcn_s_setprio(1);                                             \
    _Pragma("unroll")                                                          \
    for (int t = 0; t < 4; ++t) {                                              \
        _Pragma("unroll")                                                      \
        for (int jj = 0; jj < 2; ++jj) {                                       \
            acc[(I0)+t][(J0)+jj] = __builtin_amdgcn_mfma_f32_16x16x32_bf16(    \
                af[t][0], bf[(J0)+jj][0], acc[(I0)+t][(J0)+jj], 0, 0, 0);      \
            acc[(I0)+t][(J0)+jj] = __builtin_amdgcn_mfma_f32_16x16x32_bf16(    \
                af[t][1], bf[(J0)+jj][1], acc[(I0)+t][(J0)+jj], 0, 0, 0);      \
        }                                                                      \
    }                                                                          \
    __builtin_amdgcn_s_setprio(0);

#define MAIN_LOOP_8PHASE(PA0, PA1, PB0, PB1)                                   \
    STG(0,             PA0, 0);                                                \
    STG(8192,          PA1, 0);                                                \
    STG(16384,         PB0, 0);                                                \
    STG(24576,         PB1, 0);                                                \
    STG(32768 + 16384, PB0, 64);                                               \
    STG(32768 + 24576, PB1, 64);                                               \
    STG(32768 + 0,     PA0, 64);                                               \
    asm volatile("s_waitcnt vmcnt(6)" ::: "memory");                           \
    BARRIER();                                                                 \
    _Pragma("unroll")                                                          \
    for (int i = 0; i < 8; i++)                                                \
        _Pragma("unroll")                                                      \
        for (int j = 0; j < 4; j++) acc[i][j] = (f32x4){0.f, 0.f, 0.f, 0.f};   \
    for (int T = 0; T < 16; ++T) {                                             \
        const int cbase = (T & 1) << 15;                                       \
        const int obase = cbase ^ 32768;                                       \
        const int abase = cbase + aregw;                                       \
        const int bbase = cbase + bregw;                                       \
        const int kc1 = (T + 1 < 16 ? T + 1 : 15) * 64;                        \
        const int kc2 = (T + 2 < 16 ? T + 2 : 15) * 64;                        \
        LDA(0)                                                                 \
        LDBALL()                                                               \
        STG(obase + 8192, PA1, kc1);                                           \
        BARRIER();                                                             \
        MFMA_Q(0, 0)                                                           \
        BARRIER();                                                             \
        STG(cbase + 16384, PB0, kc2);                                          \
        BARRIER();                                                             \
        MFMA_Q(0, 2)                                                           \
        BARRIER();                                                             \
        LDA(1)                                                                 \
        STG(cbase + 24576, PB1, kc2);                                          \
        BARRIER();                                                             \
        MFMA_Q(4, 2)                                                           \
        BARRIER();                                                             \
        STG(cbase + 0, PA0, kc2);                                              \
        asm volatile("s_waitcnt vmcnt(6)" ::: "memory");                       \
        BARRIER();                                                             \
        MFMA_Q(4, 0)                                                           \
        BARRIER();                                                             \
    }                                                                          \
    asm volatile("s_waitcnt vmcnt(0)" ::: "memory");

// ---------------------------------------------------------------------------
// K2: fused P/G GEMM, 256x256-tile 8-phase.  A = xb (M=16384, K=1024):
//  z=0: P[i][f] = sum_e x[i][e]·NT[f][e]           -> pb (row-major bf16)
//  z=1: G[i][q] = sum_e x[i][e]·M[q][e] + c[q]     -> gbuf per-thread-slot
//       layout: tile(mt*4+nt)*65536 + (i*2+jp)*4096 + tid*8 + (j&1)*4 + r
// grid 512; XCD swizzle keeps 8 consecutive A-panels per XCD.
// ---------------------------------------------------------------------------
__global__ __launch_bounds__(512, 2)
void pg_gemm8(const unsigned short* __restrict__ xb,
              const unsigned short* __restrict__ ntb,
              const unsigned short* __restrict__ mb,
              const float* __restrict__ cvec,
              unsigned short* __restrict__ pb,
              unsigned short* __restrict__ gbuf) {
    extern __shared__ __align__(16) unsigned short lds_pg[];

    const int bid = blockIdx.x;
    const int logical = (bid & 7) * 64 + (bid >> 3);
    const int mt = logical >> 3;          // 0..63
    const int z  = (logical >> 2) & 1;
    const int nt = logical & 3;           // 0..3
    const int m0 = mt * 256, n0 = nt * 256;

    const unsigned short* Bm = z ? mb : ntb;

    const int tid = threadIdx.x, lane = tid & 63, w = tid >> 6;
    const int fr = lane & 15, ls = lane >> 4, f7 = fr & 7;

    const int ssl   = ((tid & 7) ^ ((tid >> 3) & 7)) * 8;      // elements
    const int soff0 = (tid >> 3) * 1024 + ssl;
    const int soff1 = soff0 + 64 * 1024;
    const int dstw  = w * 512;                                 // u16

    const unsigned short* pA0 = xb  + (size_t)m0 * 1024;
    const unsigned short* pA1 = pA0 + (size_t)128 * 1024;
    const unsigned short* pB0 = Bm  + (size_t)n0 * 1024;
    const unsigned short* pB1 = pB0 + (size_t)128 * 1024;

    const int aregw = (w >> 2) * 8192;                  // wave's A half
    const int bregw = 16384 + ((w & 3) >> 1) * 8192;    // wave's B half
    const int bro   = (w & 1) * 64;                     // n-offset in B half
    const int sl0   = (ls ^ f7) << 3;                   // kk=0 swz slot (elems)
    const int sl1   = ((4 + ls) ^ f7) << 3;             // kk=1

    f32x4 acc[8][4];
    frag8 af[4][2], bf[4][2];

    MAIN_LOOP_8PHASE(pA0, pA1, pB0, pB1)

    // epilogue
    const int wm = (w >> 2) * 128, wn = (w & 3) * 64;
    const int rb4 = ls * 4;
    if (z == 0) {
        // P: row-major store (consumed via global_load_lds row staging)
#pragma unroll
        for (int i = 0; i < 8; ++i)
#pragma unroll
            for (int j = 0; j < 4; ++j) {
                const int gm = m0 + wm + i * 16 + rb4;
                const int gn = n0 + wn + j * 16 + fr;
#pragma unroll
                for (int r = 0; r < 4; ++r)
                    pb[(size_t)(gm + r) * 1024 + gn] = f2bf(acc[i][j][r]);
            }
    } else {
        // G: per-thread-slot layout, 16 coalesced 16B stores
        float bb[4];
#pragma unroll
        for (int j = 0; j < 4; ++j) bb[j] = cvec[n0 + wn + j * 16 + fr];
        unsigned short* Gt = gbuf + ((size_t)(mt * 4 + nt) << 16) + tid * 8;
#pragma unroll
        for (int i = 0; i < 8; ++i) {
#pragma unroll
            for (int jp = 0; jp < 2; ++jp) {
                u16x8 o;
#pragma unroll
                for (int e = 0; e < 8; ++e) {
                    const int j = jp * 2 + (e >> 2), r = e & 3;
                    o[e] = f2bf(acc[i][j][r] + bb[j]);
                }
                *(u16x8*)(Gt + (size_t)(i * 2 + jp) * 4096) = o;
            }
        }
    }
}

// ---------------------------------------------------------------------------
// K3: score + exp + G-weighted row reduction, 256x256 8-phase.
// S[i][j] = sum_f P[b·T+i][f]·x[b·T+j][f] + u[i] + v[j]; p = exp(S*scale).
// G read back from per-thread-slot gbuf (identical geometry as producer).
// Partials: chunk t = jt*4+(w&3); lpart/Apart[((b*8+i0b)*16+t)*128+row],
// i0b=it*2+(w>>2); every slot written exactly once; finalize unchanged.
// grid 256.
// ---------------------------------------------------------------------------
__global__ __launch_bounds__(512, 2)
void score_attn8(const unsigned short* __restrict__ pbuf,
                 const unsigned short* __restrict__ xb,
                 const unsigned short* __restrict__ gb,
                 const float* __restrict__ u, const float* __restrict__ v,
                 float* __restrict__ lpart, float* __restrict__ Apart) {
    extern __shared__ __align__(16) unsigned short lds_pg[];

    const int bid = blockIdx.x;
    const int logical = (bid & 7) * 32 + (bid >> 3);
    const int b  = logical >> 4;          // 0..15
    const int it = (logical >> 2) & 3;    // i-tile (256 rows)
    const int jt = logical & 3;           // j-tile (256 cols)

    const int tid = threadIdx.x, lane = tid & 63, w = tid >> 6;
    const int fr = lane & 15, ls = lane >> 4, f7 = fr & 7;

    const int ssl   = ((tid & 7) ^ ((tid >> 3) & 7)) * 8;      // elements
    const int soff0 = (tid >> 3) * 1024 + ssl;
    const int soff1 = soff0 + 64 * 1024;
    const int dstw  = w * 512;                                 // u16

    const unsigned short* pA0 = pbuf + (size_t)(b * 1024 + it * 256) * 1024;
    const unsigned short* pA1 = pA0  + (size_t)128 * 1024;
    const unsigned short* pB0 = xb   + (size_t)(b * 1024 + jt * 256) * 1024;
    const unsigned short* pB1 = pB0  + (size_t)128 * 1024;

    const int aregw = (w >> 2) * 8192;
    const int bregw = 16384 + ((w & 3) >> 1) * 8192;
    const int bro   = (w & 1) * 64;
    const int sl0   = (ls ^ f7) << 3;
    const int sl1   = ((4 + ls) ^ f7) << 3;

    f32x4 acc[8][4];
    frag8 af[4][2], bf[4][2];

    MAIN_LOOP_8PHASE(pA0, pA1, pB0, pB1)

    // epilogue: p = exp((S + u[i] + v[j])*scale); reduce p and p*G over cols
    const float scale = 0.03125f;   // 1/sqrt(1024)
    const int wm = (w >> 2) * 128, wn = (w & 3) * 64;
    const float* ub = u + (size_t)b * T_ + it * 256 + wm;
    const float* vb = v + (size_t)b * T_ + jt * 256 + wn;

    float vval[4];
#pragma unroll
    for (int j = 0; j < 4; ++j) vval[j] = vb[j * 16 + fr];

    const unsigned short* Gt =
        gb + ((size_t)((b * 4 + it) * 4 + jt) << 16) + tid * 8;

    const int i0b = it * 2 + (w >> 2);
    const int tch = jt * 4 + (w & 3);
    const size_t base = ((size_t)(b * 8 + i0b) * 16 + tch) * 128;
    float* lrow = lpart + base;
    float* Arow = Apart + base;

#pragma unroll
    for (int i = 0; i < 8; ++i) {
        float uval[4];
#pragma unroll
        for (int r = 0; r < 4; ++r) uval[r] = ub[i * 16 + ls * 4 + r];
        float lp[4] = {0.f, 0.f, 0.f, 0.f}, Ap[4] = {0.f, 0.f, 0.f, 0.f};
#pragma unroll
        for (int jp = 0; jp < 2; ++jp) {
            u16x8 gv = *(const u16x8*)(Gt + (size_t)(i * 2 + jp) * 4096);
#pragma unroll
            for (int e = 0; e < 8; ++e) {
                const int j = jp * 2 + (e >> 2), r = e & 3;
                float p = __expf((acc[i][j][r] + uval[r] + vval[j]) * scale);
                lp[r] += p;
                Ap[r] += p * bf2f(gv[e]);
            }
        }
#pragma unroll
        for (int m = 1; m < 16; m <<= 1) {
#pragma unroll
            for (int r = 0; r < 4; ++r) {
                lp[r] += __shfl_xor(lp[r], m);
                Ap[r] += __shfl_xor(Ap[r], m);
            }
        }
        if (fr == 0) {
#pragma unroll
            for (int r = 0; r < 4; ++r) {
                const int row = i * 16 + ls * 4 + r;
                lrow[row] = lp[r];
                Arow[row] = Ap[r];
            }
        }
    }
}

// ---------------------------------------------------------------------------
// K4: finalize — out[b] = bfc + sum_i (sum_t Apart)/(sum_t lpart).
// Fixed summation order -> bit-deterministic.  grid (16) block 256.
// ---------------------------------------------------------------------------
__global__ __launch_bounds__(256)
void finalize(const float* __restrict__ lpart, const float* __restrict__ Apart,
              const float* __restrict__ bfc, float* __restrict__ out) {
    const int b = blockIdx.x;
    const int tid = threadIdx.x, lane = tid & 63, wave = tid >> 6;
    float s = 0.f;
#pragma unroll
    for (int p = 0; p < 4; ++p) {
        const int rg = tid + p * 256;          // 0..1023 (row index within b)
        const int i0b = rg >> 7, row = rg & 127;
        const size_t base = ((size_t)b * 8 + i0b) * 2048 + row;
        float lsum = 0.f, Asum = 0.f;
#pragma unroll
        for (int t = 0; t < 16; ++t) {         // 64-col chunks, fixed order
            lsum += lpart[base + (size_t)t * 128];
            Asum += Apart[base + (size_t)t * 128];
        }
        s += Asum / lsum;
    }
#pragma unroll
    for (int off = 32; off; off >>= 1) s += __shfl_down(s, off);
    __shared__ float ws_[4];
    if (lane == 0) ws_[wave] = s;
    __syncthreads();
    if (tid == 0) out[b] = ws_[0] + ws_[1] + ws_[2] + ws_[3] + bfc[0];
}

extern "C" void kernel_launch(void* const* d_in, const int* in_sizes, int n_in,
                              void* d_out, int out_size, void* d_ws, size_t ws_size,
                              hipStream_t stream) {
    const float* x   = (const float*)d_in[0];
    const float* Wq  = (const float*)d_in[1];
    const float* bq  = (const float*)d_in[2];
    const float* Wk  = (const float*)d_in[3];
    const float* bk  = (const float*)d_in[4];
    const float* Wv  = (const float*)d_in[5];
    const float* bv  = (const float*)d_in[6];
    const float* Wfc = (const float*)d_in[7];
    const float* bfc = (const float*)d_in[8];
    float* out = (float*)d_out;

    // one-time: allow 128 KiB dynamic LDS (host-side, capture-safe)
    static bool attr_set = false;
    if (!attr_set) {
        hipFuncSetAttribute((const void*)pg_gemm8,
                            hipFuncAttributeMaxDynamicSharedMemorySize, 131072);
        hipFuncSetAttribute((const void*)score_attn8,
                            hipFuncAttributeMaxDynamicSharedMemorySize, 131072);
        attr_set = true;
    }

    // workspace layout (~102.3 MB), every byte written before read each call:
    char* ws = (char*)d_ws;
    unsigned short* xb    = (unsigned short*)ws;                   // 32 MB
    unsigned short* ntb   = xb   + (size_t)B_ * T_ * D_;           // 2 MB
    unsigned short* mb    = ntb  + (size_t)D_ * D_;                // 2 MB
    unsigned short* pb    = mb   + (size_t)D_ * D_;                // 32 MB
    unsigned short* gbuf  = pb   + (size_t)B_ * T_ * D_;           // 32 MB
    float*          w1    = (float*)(gbuf + (size_t)B_ * T_ * T_); // 4 KB
    float*          w2    = w1 + D_;                               // 4 KB
    float*          cvec  = w2 + D_;                               // 4 KB
    float*          bkbq  = cvec + D_;                             // 16 B
    float*          u     = bkbq + 4;                              // 64 KB
    float*          v     = u + (size_t)B_ * T_;                   // 64 KB
    float*          lpart = v + (size_t)B_ * T_;                   // 1 MB
    float*          Apart = lpart + (size_t)B_ * 8 * 8 * 2 * 128;  // 1 MB

    prep_w     <<<dim3(1152),      256, 0,      stream>>>(Wq, Wk, Wfc, Wv, bq, bk, bv, ntb, mb, w1, w2, cvec, bkbq);
    cvt_x_uv   <<<dim3(4096),      256, 0,      stream>>>(x, xb, w1, w2, bkbq, u, v);
    pg_gemm8   <<<dim3(512),       512, 131072, stream>>>(xb, ntb, mb, cvec, pb, gbuf);
    score_attn8<<<dim3(256),       512, 131072, stream>>>(pb, xb, gbuf, u, v, lpart, Apart);
    finalize   <<<dim3(B_),        256, 0,      stream>>>(lpart, Apart, bfc, out);
}

// Round 5
// 277.900 us; speedup vs baseline: 1.0607x; 1.0460x over previous
//
#include <hip/hip_runtime.h>
#include <hip/hip_bf16.h>

// Problem constants
#define B_ 16
#define T_ 1024
#define D_ 1024

using frag8  = __attribute__((ext_vector_type(8))) short;   // 8 bf16 (4 VGPRs)
using f32x4  = __attribute__((ext_vector_type(4))) float;   // 4 fp32 acc
using u16x8  = __attribute__((ext_vector_type(8))) unsigned short; // 16B chunk

__device__ inline unsigned short f2bf(float f) {
    union { float f; unsigned u; } v; v.f = f;
    unsigned r = v.u + 0x7FFF + ((v.u >> 16) & 1);   // round-nearest-even
    return (unsigned short)(r >> 16);
}
__device__ inline float bf2f(unsigned short u) {
    union { unsigned u; float f; } v; v.u = ((unsigned)u) << 16;
    return v.f;
}

// ---------------------------------------------------------------------------
// K0a (FUSED): cast Wq/Wk/Wv/Wfc fp32->bf16  PLUS  wvec rows, one launch.
//  blocks [0,4096):    w = bx>>10 selects the weight; plain float4 cast.
//  blocks [4096,4864): vec rows: y=0: w1[e]=Wk[e]·bq  y=1: w2[e]=Wq[e]·bk
//                      y=2: c[q]=Wfc_row(q)·bv   (256 blocks x 4 rows each)
//  block  4864:        bkbq = bk·bq
// All parts independent (read-only inputs, disjoint outputs).
// ---------------------------------------------------------------------------
__global__ __launch_bounds__(256)
void cvt_w4x(const float* __restrict__ Wq, const float* __restrict__ Wk,
             const float* __restrict__ Wv, const float* __restrict__ Wfc,
             const float* __restrict__ bq, const float* __restrict__ bk,
             const float* __restrict__ bv,
             unsigned short* __restrict__ wqb, unsigned short* __restrict__ wkb,
             unsigned short* __restrict__ wvb, unsigned short* __restrict__ wfcb,
             float* __restrict__ w1, float* __restrict__ w2,
             float* __restrict__ cvec, float* __restrict__ bkbq) {
    const int bx = blockIdx.x;
    const int tid = threadIdx.x, lane = tid & 63, wave = tid >> 6;
    if (bx < 4096) {
        const int w = bx >> 10;
        const float* src = (w == 0) ? Wq : (w == 1) ? Wk : (w == 2) ? Wv : Wfc;
        unsigned short* dst = (w == 0) ? wqb : (w == 1) ? wkb : (w == 2) ? wvb : wfcb;
        int i = (bx & 1023) * 256 + tid;
        float4 v = ((const float4*)src)[i];
        ushort4 o;
        o.x = f2bf(v.x); o.y = f2bf(v.y); o.z = f2bf(v.z); o.w = f2bf(v.w);
        ((ushort4*)dst)[i] = o;
        return;
    }
    if (bx == 4864) {
        float s = 0.f;
#pragma unroll
        for (int p = 0; p < 4; ++p) { int i = tid + p * 256; s += bk[i] * bq[i]; }
#pragma unroll
        for (int off = 32; off; off >>= 1) s += __shfl_down(s, off);
        __shared__ float sm[4];
        if (lane == 0) sm[wave] = s;
        __syncthreads();
        if (tid == 0) bkbq[0] = sm[0] + sm[1] + sm[2] + sm[3];
        return;
    }
    const int idx = bx - 4096;          // 0..767
    const int y   = idx >> 8;           // 0..2
    const int bxx = idx & 255;
    const float* Wsrc; const float* bvv; float* outp;
    if (y == 0)      { Wsrc = Wk;  bvv = bq; outp = w1; }
    else if (y == 1) { Wsrc = Wq;  bvv = bk; outp = w2; }
    else             { Wsrc = Wfc; bvv = bv; outp = cvec; }
    const int row = bxx * 4 + wave;
    const float* r = Wsrc + (size_t)row * D_;
    float s = 0.f;
#pragma unroll
    for (int it = 0; it < 4; ++it) {
        float4 a = *(const float4*)&r[it * 256 + lane * 4];
        float4 b = *(const float4*)&bvv[it * 256 + lane * 4];
        s += a.x * b.x + a.y * b.y + a.z * b.z + a.w * b.w;
    }
#pragma unroll
    for (int off = 32; off; off >>= 1) s += __shfl_down(s, off);
    if (lane == 0) outp[row] = s;
}

// ---------------------------------------------------------------------------
// K0c: FUSED x fp32 -> bf16 cast + u/v row dots (single pass over x).
//  xb[row] = bf16(x[row]);  u[row] = x[row]·w1;  v[row] = x[row]·w2 + bkbq.
// grid 4096, block 256 (4 waves, 1 row/wave); coalesced float4/ushort4.
// ---------------------------------------------------------------------------
__global__ __launch_bounds__(256)
void cvt_x_uv(const float* __restrict__ x, unsigned short* __restrict__ xb,
              const float* __restrict__ w1, const float* __restrict__ w2,
              const float* __restrict__ bkbq,
              float* __restrict__ u, float* __restrict__ v) {
    __shared__ float s1[1024], s2[1024];
    const int tid = threadIdx.x, lane = tid & 63, wave = tid >> 6;
#pragma unroll
    for (int p = 0; p < 4; ++p) {
        int i = tid + p * 256;
        s1[i] = w1[i]; s2[i] = w2[i];
    }
    __syncthreads();
    const int row = blockIdx.x * 4 + wave;
    const float* xr = x + (size_t)row * D_;
    unsigned short* xo = xb + (size_t)row * D_;
    float du = 0.f, dv = 0.f;
#pragma unroll
    for (int k = 0; k < 4; ++k) {
        const int e0 = k * 256 + lane * 4;
        float4 a = *(const float4*)&xr[e0];
        ushort4 o;
        o.x = f2bf(a.x); o.y = f2bf(a.y); o.z = f2bf(a.z); o.w = f2bf(a.w);
        *(ushort4*)&xo[e0] = o;
        du += a.x * s1[e0] + a.y * s1[e0 + 1] + a.z * s1[e0 + 2] + a.w * s1[e0 + 3];
        dv += a.x * s2[e0] + a.y * s2[e0 + 1] + a.z * s2[e0 + 2] + a.w * s2[e0 + 3];
    }
#pragma unroll
    for (int off = 32; off; off >>= 1) {
        du += __shfl_down(du, off);
        dv += __shfl_down(dv, off);
    }
    if (lane == 0) { u[row] = du; v[row] = dv + bkbq[0]; }
}

// ---------------------------------------------------------------------------
// K1: small weight-product GEMMs (m97-style, bf16 inputs via global_load_lds
// — the r2-verified fast version; inline-fp32 variant regressed r3/r4):
//  z=0: NT[f][e] = sum_d Wq[f][d]·Wk[e][d]   -> ntb
//  z=1: M [q][e] = sum_d Wfc[q][d]·Wv[e][d]  -> mb
// grid (8, 8, 2) block 256.
// ---------------------------------------------------------------------------
__global__ __launch_bounds__(256)
void small_gemm(const unsigned short* __restrict__ wqb,
                const unsigned short* __restrict__ wkb,
                const unsigned short* __restrict__ wfcb,
                const unsigned short* __restrict__ wvb,
                unsigned short* __restrict__ ntb,
                unsigned short* __restrict__ mb) {
    __shared__ __align__(16) unsigned short As[128 * 32];
    __shared__ __align__(16) unsigned short Bs[128 * 32];

    const int z  = blockIdx.z;
    const int n0 = blockIdx.x * 128;
    const int m0 = blockIdx.y * 128;
    const unsigned short* A  = z ? wfcb : wqb;
    const unsigned short* Bm = z ? wvb  : wkb;
    unsigned short* out = z ? mb : ntb;

    const int tid = threadIdx.x, lane = tid & 63, wave = tid >> 6;
    const int wm = (wave >> 1) * 64, wn = (wave & 1) * 64;

    f32x4 acc[4][4];
#pragma unroll
    for (int i = 0; i < 4; i++)
#pragma unroll
        for (int j = 0; j < 4; j++) acc[i][j] = (f32x4){0.f, 0.f, 0.f, 0.f};

    const int srow = lane >> 2;
    const int sk   = (lane & 3) * 8;
    const int fr = lane & 15, fk = (lane >> 4) * 8;

    for (int k0 = 0; k0 < D_; k0 += 32) {
#pragma unroll
        for (int it = 0; it < 2; ++it) {
            const int rb = wave * 2 + it;
            const int r  = rb * 16 + srow;
            __builtin_amdgcn_global_load_lds(
                (const __attribute__((address_space(1))) unsigned int*)
                    (A + (size_t)(m0 + r) * D_ + k0 + sk),
                (__attribute__((address_space(3))) unsigned int*)(As + rb * 512),
                16, 0, 0);
            __builtin_amdgcn_global_load_lds(
                (const __attribute__((address_space(1))) unsigned int*)
                    (Bm + (size_t)(n0 + r) * D_ + k0 + sk),
                (__attribute__((address_space(3))) unsigned int*)(Bs + rb * 512),
                16, 0, 0);
        }
        __syncthreads();

        frag8 af[4], bff[4];
#pragma unroll
        for (int t = 0; t < 4; ++t)
            af[t] = *(const frag8*)&As[(wm + t * 16 + fr) * 32 + fk];
#pragma unroll
        for (int t = 0; t < 4; ++t)
            bff[t] = *(const frag8*)&Bs[(wn + t * 16 + fr) * 32 + fk];
#pragma unroll
        for (int i = 0; i < 4; i++)
#pragma unroll
            for (int j = 0; j < 4; j++)
                acc[i][j] = __builtin_amdgcn_mfma_f32_16x16x32_bf16(
                    af[i], bff[j], acc[i][j], 0, 0, 0);
        __syncthreads();
    }

    const int col   = lane & 15;
    const int rbase = (lane >> 4) * 4;
#pragma unroll
    for (int i = 0; i < 4; i++) {
#pragma unroll
        for (int j = 0; j < 4; j++) {
            int gn = n0 + wn + j * 16 + col;
#pragma unroll
            for (int r = 0; r < 4; r++) {
                int gm = m0 + wm + i * 16 + rbase + r;
                out[(size_t)gm * D_ + gn] = f2bf(acc[i][j][r]);
            }
        }
    }
}

// ---------------------------------------------------------------------------
// Shared 256x256 8-phase main-loop machinery — ROUND-2 VERIFIED SCHEDULE:
//  P0 {LDA(i0)+LDBALL; stage (T+1).Ah1}, P1 {stage (T+2).Bh0},
//  P2 {LDA(i1); stage (T+2).Bh1}, P3 {stage (T+2).Ah0; vmcnt(6)}.
// Region safety: B fully read in P0, A fully read by P2; every stage lands
// >=1 end-barrier after the last read of its region; vmcnt(6) at T.P3
// drains through T.P0 (tile T+1 resident), leaving 6 in flight.  Prologue
// = 7 pairs, same invariant.  Tail stages clamp kcol to tile 15.
// ---------------------------------------------------------------------------
#define BARRIER() do { __builtin_amdgcn_s_barrier(); \
                       __builtin_amdgcn_sched_barrier(0); } while (0)

#define STG(ldsoff, panel, kcol)                                               \
    do {                                                                       \
        __builtin_amdgcn_global_load_lds(                                      \
            (const __attribute__((address_space(1))) unsigned int*)            \
                ((panel) + soff0 + (kcol)),                                    \
            (__attribute__((address_space(3))) unsigned int*)                  \
                (lds_pg + (ldsoff) + dstw), 16, 0, 0);                         \
        __builtin_amdgcn_global_load_lds(                                      \
            (const __attribute__((address_space(1))) unsigned int*)            \
                ((panel) + soff1 + (kcol)),                                    \
            (__attribute__((address_space(3))) unsigned int*)                  \
                (lds_pg + (ldsoff) + 4096 + dstw), 16, 0, 0);                  \
    } while (0)

#define LDA(IH)                                                                \
    _Pragma("unroll")                                                          \
    for (int t = 0; t < 4; ++t) {                                              \
        const int rbb = abase + ((IH) * 64 + t * 16 + fr) * 64;                \
        af[t][0] = *(const frag8*)&lds_pg[rbb + sl0];                          \
        af[t][1] = *(const frag8*)&lds_pg[rbb + sl1];                          \
    }
#define LDBALL()                                                               \
    _Pragma("unroll")                                                          \
    for (int j = 0; j < 4; ++j) {                                              \
        const int rbb = bbase + (bro + j * 16 + fr) * 64;                      \
        bf[j][0] = *(const frag8*)&lds_pg[rbb + sl0];                          \
        bf[j][1] = *(const frag8*)&lds_pg[rbb + sl1];                          \
    }
#define MFMA_Q(I0, J0)                                                         \
    __builtin_amdgcn_s_setprio(1);                                             \
    _Pragma("unroll")                                                          \
    for (int t = 0; t < 4; ++t) {                                              \
        _Pragma("unroll")                                                      \
        for (int jj = 0; jj < 2; ++jj) {                                       \
            acc[(I0)+t][(J0)+jj] = __builtin_amdgcn_mfma_f32_16x16x32_bf16(    \
                af[t][0], bf[(J0)+jj][0], acc[(I0)+t][(J0)+jj], 0, 0, 0);      \
            acc[(I0)+t][(J0)+jj] = __builtin_amdgcn_mfma_f32_16x16x32_bf16(    \
                af[t][1], bf[(J0)+jj][1], acc[(I0)+t][(J0)+jj], 0, 0, 0);      \
        }                                                                      \
    }                                                                          \
    __builtin_amdgcn_s_setprio(0);

#define MAIN_LOOP_8PHASE(PA0, PA1, PB0, PB1)                                   \
    STG(0,             PA0, 0);                                                \
    STG(8192,          PA1, 0);                                                \
    STG(16384,         PB0, 0);                                                \
    STG(24576,         PB1, 0);                                                \
    STG(32768 + 16384, PB0, 64);                                               \
    STG(32768 + 24576, PB1, 64);                                               \
    STG(32768 + 0,     PA0, 64);                                               \
    asm volatile("s_waitcnt vmcnt(6)" ::: "memory");                           \
    BARRIER();                                                                 \
    _Pragma("unroll")                                                          \
    for (int i = 0; i < 8; i++)                                                \
        _Pragma("unroll")                                                      \
        for (int j = 0; j < 4; j++) acc[i][j] = (f32x4){0.f, 0.f, 0.f, 0.f};   \
    for (int T = 0; T < 16; ++T) {                                             \
        const int cbase = (T & 1) << 15;                                       \
        const int obase = cbase ^ 32768;                                       \
        const int abase = cbase + aregw;                                       \
        const int bbase = cbase + bregw;                                       \
        const int kc1 = (T + 1 < 16 ? T + 1 : 15) * 64;                        \
        const int kc2 = (T + 2 < 16 ? T + 2 : 15) * 64;                        \
        LDA(0)                                                                 \
        LDBALL()                                                               \
        STG(obase + 8192, PA1, kc1);                                           \
        BARRIER();                                                             \
        MFMA_Q(0, 0)                                                           \
        BARRIER();                                                             \
        STG(cbase + 16384, PB0, kc2);                                          \
        BARRIER();                                                             \
        MFMA_Q(0, 2)                                                           \
        BARRIER();                                                             \
        LDA(1)                                                                 \
        STG(cbase + 24576, PB1, kc2);                                          \
        BARRIER();                                                             \
        MFMA_Q(4, 2)                                                           \
        BARRIER();                                                             \
        STG(cbase + 0, PA0, kc2);                                              \
        asm volatile("s_waitcnt vmcnt(6)" ::: "memory");                       \
        BARRIER();                                                             \
        MFMA_Q(4, 0)                                                           \
        BARRIER();                                                             \
    }                                                                          \
    asm volatile("s_waitcnt vmcnt(0)" ::: "memory");

// ---------------------------------------------------------------------------
// K2: fused P/G GEMM, 256x256-tile 8-phase.  A = xb (M=16384, K=1024):
//  z=0: P[i][f] = sum_e x[i][e]·NT[f][e]  -> pb (row-major bf16).  NEW:
//       epilogue transposes through LDS (free after the main loop; each
//       wave owns a private 16KB scratch) so stores are 16B coalesced
//       (8 full 128B lines per inst) instead of 128 scattered ushort
//       stores/thread.  Same single f2bf rounding -> bit-identical.
//  z=1: G[i][q] = sum_e x[i][e]·M[q][e] + c[q]  -> gbuf per-thread-slot
//       layout: tile(mt*4+nt)*65536 + (i*2+jp)*4096 + tid*8 + (j&1)*4 + r
// grid 512; XCD swizzle keeps 8 consecutive A-panels per XCD.
// ---------------------------------------------------------------------------
__global__ __launch_bounds__(512, 2)
void pg_gemm8(const unsigned short* __restrict__ xb,
              const unsigned short* __restrict__ ntb,
              const unsigned short* __restrict__ mb,
              const float* __restrict__ cvec,
              unsigned short* __restrict__ pb,
              unsigned short* __restrict__ gbuf) {
    extern __shared__ __align__(16) unsigned short lds_pg[];

    const int bid = blockIdx.x;
    const int logical = (bid & 7) * 64 + (bid >> 3);
    const int mt = logical >> 3;          // 0..63
    const int z  = (logical >> 2) & 1;
    const int nt = logical & 3;           // 0..3
    const int m0 = mt * 256, n0 = nt * 256;

    const unsigned short* Bm = z ? mb : ntb;

    const int tid = threadIdx.x, lane = tid & 63, w = tid >> 6;
    const int fr = lane & 15, ls = lane >> 4, f7 = fr & 7;

    const int ssl   = ((tid & 7) ^ ((tid >> 3) & 7)) * 8;      // elements
    const int soff0 = (tid >> 3) * 1024 + ssl;
    const int soff1 = soff0 + 64 * 1024;
    const int dstw  = w * 512;                                 // u16

    const unsigned short* pA0 = xb  + (size_t)m0 * 1024;
    const unsigned short* pA1 = pA0 + (size_t)128 * 1024;
    const unsigned short* pB0 = Bm  + (size_t)n0 * 1024;
    const unsigned short* pB1 = pB0 + (size_t)128 * 1024;

    const int aregw = (w >> 2) * 8192;                  // wave's A half
    const int bregw = 16384 + ((w & 3) >> 1) * 8192;    // wave's B half
    const int bro   = (w & 1) * 64;                     // n-offset in B half
    const int sl0   = (ls ^ f7) << 3;                   // kk=0 swz slot (elems)
    const int sl1   = ((4 + ls) ^ f7) << 3;             // kk=1

    f32x4 acc[8][4];
    frag8 af[4][2], bf[4][2];

    MAIN_LOOP_8PHASE(pA0, pA1, pB0, pB1)

    // epilogue
    const int wm = (w >> 2) * 128, wn = (w & 3) * 64;
    if (z == 0) {
        // P: LDS transpose -> coalesced row-major 16B stores.
        // Wave-private scratch (16KB): XOR-swizzled [128][64] image:
        //   elem(r,c64) at r*64 + ((c64>>3)^(r&7))*8 + (c64&7).
        // Writes ~2-way conflict; b128 reads cover full 1KB -> balanced.
        unsigned short* sc = lds_pg + w * 8192;
#pragma unroll
        for (int i = 0; i < 8; ++i) {
#pragma unroll
            for (int j = 0; j < 4; ++j) {
#pragma unroll
                for (int r = 0; r < 4; ++r) {
                    const int r128 = i * 16 + ls * 4 + r;
                    const int c64  = j * 16 + fr;
                    const int eidx = r128 * 64 +
                        (((c64 >> 3) ^ (r128 & 7)) << 3) + (c64 & 7);
                    sc[eidx] = f2bf(acc[i][j][r]);
                }
            }
        }
        // same-wave read-back (compiler orders via lgkmcnt; no barrier)
#pragma unroll
        for (int t = 0; t < 16; ++t) {
            const int r128 = t * 8 + (lane >> 3);
            const int s    = lane & 7;
            u16x8 vv = *(const u16x8*)&sc[r128 * 64 + ((s ^ (r128 & 7)) << 3)];
            *(u16x8*)(pb + (size_t)(m0 + wm + r128) * 1024 + n0 + wn + s * 8) = vv;
        }
    } else {
        // G: per-thread-slot layout, 16 coalesced 16B stores
        float bb[4];
#pragma unroll
        for (int j = 0; j < 4; ++j) bb[j] = cvec[n0 + wn + j * 16 + fr];
        unsigned short* Gt = gbuf + ((size_t)(mt * 4 + nt) << 16) + tid * 8;
#pragma unroll
        for (int i = 0; i < 8; ++i) {
#pragma unroll
            for (int jp = 0; jp < 2; ++jp) {
                u16x8 o;
#pragma unroll
                for (int e = 0; e < 8; ++e) {
                    const int j = jp * 2 + (e >> 2), r = e & 3;
                    o[e] = f2bf(acc[i][j][r] + bb[j]);
                }
                *(u16x8*)(Gt + (size_t)(i * 2 + jp) * 4096) = o;
            }
        }
    }
}

// ---------------------------------------------------------------------------
// K3: score + exp + G-weighted row reduction, 256x256 8-phase.
// S[i][j] = sum_f P[b·T+i][f]·x[b·T+j][f] + u[i] + v[j]; p = exp(S*scale).
// G read back from per-thread-slot gbuf (identical geometry as producer).
// Partials: chunk t = jt*4+(w&3); lpart/Apart[((b*8+i0b)*16+t)*128+row],
// i0b=it*2+(w>>2); every slot written exactly once; finalize unchanged.
// grid 256.
// ---------------------------------------------------------------------------
__global__ __launch_bounds__(512, 2)
void score_attn8(const unsigned short* __restrict__ pbuf,
                 const unsigned short* __restrict__ xb,
                 const unsigned short* __restrict__ gb,
                 const float* __restrict__ u, const float* __restrict__ v,
                 float* __restrict__ lpart, float* __restrict__ Apart) {
    extern __shared__ __align__(16) unsigned short lds_pg[];

    const int bid = blockIdx.x;
    const int logical = (bid & 7) * 32 + (bid >> 3);
    const int b  = logical >> 4;          // 0..15
    const int it = (logical >> 2) & 3;    // i-tile (256 rows)
    const int jt = logical & 3;           // j-tile (256 cols)

    const int tid = threadIdx.x, lane = tid & 63, w = tid >> 6;
    const int fr = lane & 15, ls = lane >> 4, f7 = fr & 7;

    const int ssl   = ((tid & 7) ^ ((tid >> 3) & 7)) * 8;      // elements
    const int soff0 = (tid >> 3) * 1024 + ssl;
    const int soff1 = soff0 + 64 * 1024;
    const int dstw  = w * 512;                                 // u16

    const unsigned short* pA0 = pbuf + (size_t)(b * 1024 + it * 256) * 1024;
    const unsigned short* pA1 = pA0  + (size_t)128 * 1024;
    const unsigned short* pB0 = xb   + (size_t)(b * 1024 + jt * 256) * 1024;
    const unsigned short* pB1 = pB0  + (size_t)128 * 1024;

    const int aregw = (w >> 2) * 8192;
    const int bregw = 16384 + ((w & 3) >> 1) * 8192;
    const int bro   = (w & 1) * 64;
    const int sl0   = (ls ^ f7) << 3;
    const int sl1   = ((4 + ls) ^ f7) << 3;

    f32x4 acc[8][4];
    frag8 af[4][2], bf[4][2];

    MAIN_LOOP_8PHASE(pA0, pA1, pB0, pB1)

    // epilogue: p = exp((S + u[i] + v[j])*scale); reduce p and p*G over cols
    const float scale = 0.03125f;   // 1/sqrt(1024)
    const int wm = (w >> 2) * 128, wn = (w & 3) * 64;
    const float* ub = u + (size_t)b * T_ + it * 256 + wm;
    const float* vb = v + (size_t)b * T_ + jt * 256 + wn;

    float vval[4];
#pragma unroll
    for (int j = 0; j < 4; ++j) vval[j] = vb[j * 16 + fr];

    const unsigned short* Gt =
        gb + ((size_t)((b * 4 + it) * 4 + jt) << 16) + tid * 8;

    const int i0b = it * 2 + (w >> 2);
    const int tch = jt * 4 + (w & 3);
    const size_t base = ((size_t)(b * 8 + i0b) * 16 + tch) * 128;
    float* lrow = lpart + base;
    float* Arow = Apart + base;

#pragma unroll
    for (int i = 0; i < 8; ++i) {
        float uval[4];
#pragma unroll
        for (int r = 0; r < 4; ++r) uval[r] = ub[i * 16 + ls * 4 + r];
        float lp[4] = {0.f, 0.f, 0.f, 0.f}, Ap[4] = {0.f, 0.f, 0.f, 0.f};
#pragma unroll
        for (int jp = 0; jp < 2; ++jp) {
            u16x8 gv = *(const u16x8*)(Gt + (size_t)(i * 2 + jp) * 4096);
#pragma unroll
            for (int e = 0; e < 8; ++e) {
                const int j = jp * 2 + (e >> 2), r = e & 3;
                float p = __expf((acc[i][j][r] + uval[r] + vval[j]) * scale);
                lp[r] += p;
                Ap[r] += p * bf2f(gv[e]);
            }
        }
#pragma unroll
        for (int m = 1; m < 16; m <<= 1) {
#pragma unroll
            for (int r = 0; r < 4; ++r) {
                lp[r] += __shfl_xor(lp[r], m);
                Ap[r] += __shfl_xor(Ap[r], m);
            }
        }
        if (fr == 0) {
#pragma unroll
            for (int r = 0; r < 4; ++r) {
                const int row = i * 16 + ls * 4 + r;
                lrow[row] = lp[r];
                Arow[row] = Ap[r];
            }
        }
    }
}

// ---------------------------------------------------------------------------
// K4: finalize — out[b] = bfc + sum_i (sum_t Apart)/(sum_t lpart).
// Fixed summation order -> bit-deterministic.  grid (16) block 256.
// ---------------------------------------------------------------------------
__global__ __launch_bounds__(256)
void finalize(const float* __restrict__ lpart, const float* __restrict__ Apart,
              const float* __restrict__ bfc, float* __restrict__ out) {
    const int b = blockIdx.x;
    const int tid = threadIdx.x, lane = tid & 63, wave = tid >> 6;
    float s = 0.f;
#pragma unroll
    for (int p = 0; p < 4; ++p) {
        const int rg = tid + p * 256;          // 0..1023 (row index within b)
        const int i0b = rg >> 7, row = rg & 127;
        const size_t base = ((size_t)b * 8 + i0b) * 2048 + row;
        float lsum = 0.f, Asum = 0.f;
#pragma unroll
        for (int t = 0; t < 16; ++t) {         // 64-col chunks, fixed order
            lsum += lpart[base + (size_t)t * 128];
            Asum += Apart[base + (size_t)t * 128];
        }
        s += Asum / lsum;
    }
#pragma unroll
    for (int off = 32; off; off >>= 1) s += __shfl_down(s, off);
    __shared__ float ws_[4];
    if (lane == 0) ws_[wave] = s;
    __syncthreads();
    if (tid == 0) out[b] = ws_[0] + ws_[1] + ws_[2] + ws_[3] + bfc[0];
}

extern "C" void kernel_launch(void* const* d_in, const int* in_sizes, int n_in,
                              void* d_out, int out_size, void* d_ws, size_t ws_size,
                              hipStream_t stream) {
    const float* x   = (const float*)d_in[0];
    const float* Wq  = (const float*)d_in[1];
    const float* bq  = (const float*)d_in[2];
    const float* Wk  = (const float*)d_in[3];
    const float* bk  = (const float*)d_in[4];
    const float* Wv  = (const float*)d_in[5];
    const float* bv  = (const float*)d_in[6];
    const float* Wfc = (const float*)d_in[7];
    const float* bfc = (const float*)d_in[8];
    float* out = (float*)d_out;

    // one-time: allow 128 KiB dynamic LDS (host-side, capture-safe)
    static bool attr_set = false;
    if (!attr_set) {
        hipFuncSetAttribute((const void*)pg_gemm8,
                            hipFuncAttributeMaxDynamicSharedMemorySize, 131072);
        hipFuncSetAttribute((const void*)score_attn8,
                            hipFuncAttributeMaxDynamicSharedMemorySize, 131072);
        attr_set = true;
    }

    // workspace layout (~110.4 MB), every byte written before read each call:
    char* ws = (char*)d_ws;
    unsigned short* xb    = (unsigned short*)ws;                   // 32 MB
    unsigned short* wqb   = xb   + (size_t)B_ * T_ * D_;           // 2 MB
    unsigned short* wkb   = wqb  + (size_t)D_ * D_;                // 2 MB
    unsigned short* wvb   = wkb  + (size_t)D_ * D_;                // 2 MB
    unsigned short* wfcb  = wvb  + (size_t)D_ * D_;                // 2 MB
    unsigned short* ntb   = wfcb + (size_t)D_ * D_;                // 2 MB
    unsigned short* mb    = ntb  + (size_t)D_ * D_;                // 2 MB
    unsigned short* pb    = mb   + (size_t)D_ * D_;                // 32 MB
    unsigned short* gbuf  = pb   + (size_t)B_ * T_ * D_;           // 32 MB
    float*          w1    = (float*)(gbuf + (size_t)B_ * T_ * T_); // 4 KB
    float*          w2    = w1 + D_;                               // 4 KB
    float*          cvec  = w2 + D_;                               // 4 KB
    float*          bkbq  = cvec + D_;                             // 16 B
    float*          u     = bkbq + 4;                              // 64 KB
    float*          v     = u + (size_t)B_ * T_;                   // 64 KB
    float*          lpart = v + (size_t)B_ * T_;                   // 1 MB
    float*          Apart = lpart + (size_t)B_ * 8 * 8 * 2 * 128;  // 1 MB

    cvt_w4x    <<<dim3(4865),      256, 0,      stream>>>(Wq, Wk, Wv, Wfc, bq, bk, bv,
                                                          wqb, wkb, wvb, wfcb,
                                                          w1, w2, cvec, bkbq);
    small_gemm <<<dim3(8, 8, 2),   256, 0,      stream>>>(wqb, wkb, wfcb, wvb, ntb, mb);
    cvt_x_uv   <<<dim3(4096),      256, 0,      stream>>>(x, xb, w1, w2, bkbq, u, v);
    pg_gemm8   <<<dim3(512),       512, 131072, stream>>>(xb, ntb, mb, cvec, pb, gbuf);
    score_attn8<<<dim3(256),       512, 131072, stream>>>(pb, xb, gbuf, u, v, lpart, Apart);
    finalize   <<<dim3(B_),        256, 0,      stream>>>(lpart, Apart, bfc, out);
}